// Round 9
// baseline (114.584 us; speedup 1.0000x reference)
//
#include <hip/hip_runtime.h>
#include <hip/hip_bf16.h>

// QueryGrouper: ball_query (first-K-in-index-order within radius) + grouping.
// B=4, N=8192, M=2048, C=128, K=32, radius=0.1, use_xyz from out_size.
//
// R9: SPLIT DIAGNOSTIC. R8 showed marginal store-pass = 16us (at write
// roofline) yet total gather = 86us -> ~50us unaccounted, either in phase A
// (idx prefetch + feat staging) or in the FIRST (cold-line) store pass.
// This round: phase A x2 (keep-alive asm on pass-0 results) + phase B x3.
// dur_us ~155 => phase A is the cost; ~100 => cold-store pass is the cost.
// Either way gather (>=91us) finally enters rocprof top-5 with counters.

#define K_NEIGH 32
// f32(0.010000000000000002) — matches JAX weak-typed radius*radius bit-exactly.
#define R2_F32 0.009999999776482582f
#define CCH 128
#define NPTS 8192
#define MQ 2048

__global__ __launch_bounds__(256) void ball_query_xyz_kernel(
    const float* __restrict__ xyz,      // (B,3,N)
    const float* __restrict__ new_xyz,  // (B,3,M)
    int* __restrict__ idxb,             // (B*M, K)
    float* __restrict__ out0,           // (B, CO, M, K)
    float* __restrict__ out1,           // (B, 3, M, K)
    int N, int M, int C, int use_xyz)
{
    __shared__ int lidx[4][K_NEIGH];
    const int wave = threadIdx.x >> 6;
    const int lane = threadIdx.x & 63;
    const int q = blockIdx.x * 4 + wave;           // query id in [0, B*M)
    const int b = q / M;
    const int m = q - b * M;

    const float* xb = xyz + (size_t)b * 3 * N;
    const float* nb = new_xyz + (size_t)b * 3 * M;
    const float qx = nb[m];
    const float qy = nb[M + m];
    const float qz = nb[2 * M + m];

    int cnt = 0;
    int first_found = 0;   // pad value: first in-ball index, or 0 if none

    for (int t0 = 0; t0 < N; t0 += 64) {
        const int i = t0 + lane;
        // match JAX: sub, square (no FMA), left-to-right sum, all f32 RN
        const float dx = xb[i]         - qx;
        const float dy = xb[N + i]     - qy;
        const float dz = xb[2 * N + i] - qz;
        const float d2 = __fadd_rn(__fadd_rn(__fmul_rn(dx, dx), __fmul_rn(dy, dy)),
                                   __fmul_rn(dz, dz));
        const bool in_ball = d2 < R2_F32;
        const unsigned long long mask = __ballot(in_ball);
        if (mask) {
            if (cnt == 0) {
                first_found = t0 + (__ffsll((unsigned long long)mask) - 1);
            }
            if (in_ball) {
                const int pos = cnt + __popcll(mask & ((1ull << lane) - 1ull));
                if (pos < K_NEIGH) lidx[wave][pos] = i;
            }
            cnt += __popcll(mask);
            if (cnt >= K_NEIGH) break;   // first K found (in index order)
        }
    }

    // make this wave's LDS writes visible to its own lanes
    asm volatile("s_waitcnt lgkmcnt(0)" ::: "memory");

    if (lane < K_NEIGH) {
        const int j = (lane < cnt) ? lidx[wave][lane] : first_found;
        idxb[(size_t)q * K_NEIGH + lane] = j;
        const float gx = xb[j]         - qx;
        const float gy = xb[N + j]     - qy;
        const float gz = xb[2 * N + j] - qz;
        const size_t MK = (size_t)M * K_NEIGH;
        const size_t o1 = (size_t)b * 3 * MK + (size_t)m * K_NEIGH + lane;
        out1[o1]          = gx;
        out1[o1 + MK]     = gy;
        out1[o1 + 2 * MK] = gz;
        if (use_xyz) {
            const size_t o0 = (size_t)b * (C + 3) * MK + (size_t)m * K_NEIGH + lane;
            out0[o0]          = gx;
            out0[o0 + MK]     = gy;
            out0[o0 + 2 * MK] = gz;
        }
    }
}

// Fixed geometry: B=4, N=8192, M=2048, C=128. Grid = 256 blocks x 1024 thr.
// bid -> b = (bid&7)>>1, cg = ((bid>>3)<<1)|(bid&1).
// DIAGNOSTIC: phase A x2 (idx prefetch + 64KB feat stage), phase B x3
// (8x ds_read_b32 + 2x float4 store per iter).
__global__ __launch_bounds__(1024, 4) void gather_diag_kernel(
    const float* __restrict__ feat,  // (B,C,N)
    const int* __restrict__ idxb,    // (B*M,K)
    float* __restrict__ out0,        // (B,CO,M,K)
    int use_xyz)
{
    __shared__ float sf[2 * NPTS];   // 64 KB: [0,N) = ch c0, [N,2N) = ch c0+1

    const int t   = threadIdx.x;
    const int bid = blockIdx.x;
    const int b   = (bid & 7) >> 1;                 // 0..3
    const int cg  = ((bid >> 3) << 1) | (bid & 1);  // 0..63
    const int c0  = cg * 2;

    const int4* ip4 = (const int4*)(idxb + (size_t)b * MQ * K_NEIGH);
    const float4* fv = (const float4*)(feat + ((size_t)b * CCH + c0) * NPTS);

    int4 jj[16];

    // ---- Phase A x2 ----
    for (int ap = 0; ap < 2; ++ap) {
        #pragma unroll
        for (int i = 0; i < 16; ++i) jj[i] = ip4[i * 1024 + t];
        #pragma unroll
        for (int r = 0; r < 4; ++r)
            ((float4*)sf)[t + r * 1024] = fv[t + r * 1024];
        __syncthreads();
        if (ap == 0) {
            // keep pass-0 loads live (rule #17) so the compiler can't delete them
            #pragma unroll
            for (int i = 0; i < 16; ++i)
                asm volatile("" :: "v"(jj[i].x), "v"(jj[i].y),
                                   "v"(jj[i].z), "v"(jj[i].w));
        }
    }

    // ---- Phase B x3: pure LDS-read + 16B/lane stores ----
    const size_t MK = (size_t)MQ * K_NEIGH;
    const int CO   = use_xyz ? (CCH + 3) : CCH;
    const int coff = use_xyz ? 3 : 0;
    float* o0 = out0 + ((size_t)b * CO + coff + c0) * MK;
    float* o1 = o0 + MK;

    for (int pass = 0; pass < 3; ++pass) {
        #pragma unroll
        for (int i = 0; i < 16; ++i) {
            const int p = i * 4096 + 4 * t;      // flat (m,k) base, k-aligned x4
            const int4 j4 = jj[i];
            float4 s0, s1;
            s0.x = sf[j4.x]; s0.y = sf[j4.y]; s0.z = sf[j4.z]; s0.w = sf[j4.w];
            s1.x = sf[NPTS + j4.x]; s1.y = sf[NPTS + j4.y];
            s1.z = sf[NPTS + j4.z]; s1.w = sf[NPTS + j4.w];
            *(float4*)(o0 + p) = s0;
            *(float4*)(o1 + p) = s1;
        }
        __syncthreads();   // fence between passes (prevents dead-store elim)
    }
}

// Fallback gather (any shape): R1 structure.
__global__ __launch_bounds__(256) void gather_kernel(
    const float* __restrict__ xyz, const float* __restrict__ new_xyz,
    const float* __restrict__ feat, const int* __restrict__ idxb,
    float* __restrict__ out0, float* __restrict__ out1,
    int N, int M, int C, int use_xyz)
{
    const int tid = threadIdx.x;
    const int k = tid & 31;
    const int mloc = tid >> 5;
    const int mchunks = M >> 3;
    const int b = blockIdx.x / mchunks;
    const int m = (blockIdx.x - b * mchunks) * 8 + mloc;
    const int q = b * M + m;
    const int j = idxb[(size_t)q * K_NEIGH + k];
    const size_t xb = (size_t)b * 3 * N;
    const size_t nb = (size_t)b * 3 * M;
    const float gx = xyz[xb + j]         - new_xyz[nb + m];
    const float gy = xyz[xb + N + j]     - new_xyz[nb + M + m];
    const float gz = xyz[xb + 2 * N + j] - new_xyz[nb + 2 * M + m];
    const size_t MK = (size_t)M * K_NEIGH;
    const size_t o1 = (size_t)b * 3 * MK + (size_t)m * K_NEIGH + k;
    out1[o1] = gx; out1[o1 + MK] = gy; out1[o1 + 2 * MK] = gz;
    const int CO = use_xyz ? (C + 3) : C;
    size_t o0 = (size_t)b * CO * MK + (size_t)m * K_NEIGH + k;
    if (use_xyz) {
        out0[o0] = gx; out0[o0 + MK] = gy; out0[o0 + 2 * MK] = gz;
        o0 += 3 * MK;
    }
    const float* fb = feat + (size_t)b * C * N;
    #pragma unroll 4
    for (int c = 0; c < C; c += 4) {
        const float v0 = fb[(size_t)c * N + j];
        const float v1 = fb[(size_t)(c + 1) * N + j];
        const float v2 = fb[(size_t)(c + 2) * N + j];
        const float v3 = fb[(size_t)(c + 3) * N + j];
        out0[o0 + (size_t)c * MK]       = v0;
        out0[o0 + (size_t)(c + 1) * MK] = v1;
        out0[o0 + (size_t)(c + 2) * MK] = v2;
        out0[o0 + (size_t)(c + 3) * MK] = v3;
    }
}

extern "C" void kernel_launch(void* const* d_in, const int* in_sizes, int n_in,
                              void* d_out, int out_size, void* d_ws, size_t ws_size,
                              hipStream_t stream) {
    const float* new_xyz = (const float*)d_in[0];   // (B,3,M)
    const float* xyz     = (const float*)d_in[1];   // (B,3,N)
    const float* feat    = (const float*)d_in[2];   // (B,C,N)

    const int B = 4;                       // fixed by harness setup
    const int M = in_sizes[0] / (3 * B);   // 2048
    const int N = in_sizes[1] / (3 * B);   // 8192
    const int C = in_sizes[2] / (B * N);   // 128

    const long long sz_with = (long long)B * (C + 6) * M * K_NEIGH;
    const int use_xyz = (out_size == sz_with) ? 1 : 0;

    float* out0 = (float*)d_out;
    float* out1 = out0 + (size_t)B * (use_xyz ? (C + 3) : C) * M * K_NEIGH;

    int* idxb = (int*)d_ws;  // B*M*K ints = 1 MB
    const size_t idx_bytes = (size_t)B * M * K_NEIGH * sizeof(int);

    const bool fast = (B == 4) && (N == NPTS) && (M == MQ) && (C == CCH)
                      && (ws_size >= idx_bytes);

    ball_query_xyz_kernel<<<(B * M) / 4, 256, 0, stream>>>(
        xyz, new_xyz, idxb, out0, out1, N, M, C, use_xyz);

    if (fast) {
        gather_diag_kernel<<<256, 1024, 0, stream>>>(feat, idxb, out0, use_xyz);
    } else {
        gather_kernel<<<B * (M / 8), 256, 0, stream>>>(xyz, new_xyz, feat, idxb,
                                                       out0, out1, N, M, C, use_xyz);
    }
}

// Round 10
// 62.605 us; speedup vs baseline: 1.8303x; 1.8303x over previous
//
#include <hip/hip_runtime.h>
#include <hip/hip_bf16.h>

// QueryGrouper: ball_query (first-K-in-index-order within radius) + grouping.
// B=4, N=8192, M=2048, C=128, K=32, radius=0.1, use_xyz from out_size.
//
// R10: accounting from R7/R8/R9 marginals shows ball ~30us (serial
// load->ballot->break chain, 128 iters) and gather-store pass ~39us; the old
// "ball=7us" anchor was a cross-probe artifact (rocprof-isolated vs in-graph).
// Fixes: (1) ball unrolled x4 with NO early-exit -> compiler can pipeline the
// 12 loads per group; (2) gather = R7 one-pass structure + nontemporal float4
// stores (fill kernel's FETCH~14MB proves no-RFO writes are possible).

#define K_NEIGH 32
// f32(0.010000000000000002) — matches JAX weak-typed radius*radius bit-exactly.
#define R2_F32 0.009999999776482582f
#define CCH 128
#define NPTS 8192
#define MQ 2048

typedef float f32x4 __attribute__((ext_vector_type(4)));

__global__ __launch_bounds__(256) void ball_query_xyz_kernel(
    const float* __restrict__ xyz,      // (B,3,N)
    const float* __restrict__ new_xyz,  // (B,3,M)
    int* __restrict__ idxb,             // (B*M, K)
    float* __restrict__ out0,           // (B, CO, M, K)
    float* __restrict__ out1,           // (B, 3, M, K)
    int N, int M, int C, int use_xyz)
{
    __shared__ int lidx[4][K_NEIGH];
    const int wave = threadIdx.x >> 6;
    const int lane = threadIdx.x & 63;
    const int q = blockIdx.x * 4 + wave;           // query id in [0, B*M)
    const int b = q / M;
    const int m = q - b * M;

    const float* xb = xyz + (size_t)b * 3 * N;
    const float* x0 = xb;
    const float* x1 = xb + N;
    const float* x2 = xb + 2 * N;
    const float* nb = new_xyz + (size_t)b * 3 * M;
    const float qx = nb[m];
    const float qy = nb[M + m];
    const float qz = nb[2 * M + m];

    int cnt = 0;
    int ff  = 0;   // pad value: first in-ball index, or 0 if none
    const unsigned long long below = (1ull << lane) - 1ull;

    // full scan, unrolled x4: loads of a group are independent and coalesced;
    // only the cheap cnt/ballot bookkeeping is serial. No break (expected
    // hit count ~34 vs K=32 meant the old break almost never fired anyway).
    for (int t0 = 0; t0 < N; t0 += 256) {
        const int i = t0 + lane;
        const float ax0 = x0[i];       const float ay0 = x1[i];       const float az0 = x2[i];
        const float ax1 = x0[i + 64];  const float ay1 = x1[i + 64];  const float az1 = x2[i + 64];
        const float ax2 = x0[i + 128]; const float ay2 = x1[i + 128]; const float az2 = x2[i + 128];
        const float ax3 = x0[i + 192]; const float ay3 = x1[i + 192]; const float az3 = x2[i + 192];

        // match JAX: sub, square (no FMA), left-to-right sum, all f32 RN
        #define D2(ax, ay, az) \
            __fadd_rn(__fadd_rn(__fmul_rn((ax) - qx, (ax) - qx), \
                                __fmul_rn((ay) - qy, (ay) - qy)), \
                      __fmul_rn((az) - qz, (az) - qz))
        const bool in0 = D2(ax0, ay0, az0) < R2_F32;
        const bool in1 = D2(ax1, ay1, az1) < R2_F32;
        const bool in2 = D2(ax2, ay2, az2) < R2_F32;
        const bool in3 = D2(ax3, ay3, az3) < R2_F32;
        #undef D2

        const unsigned long long m0 = __ballot(in0);
        const unsigned long long m1 = __ballot(in1);
        const unsigned long long m2 = __ballot(in2);
        const unsigned long long m3 = __ballot(in3);

        #define SUBIT(mm, inn, ii)                                            \
            if (mm) {                                                         \
                if (cnt == 0) ff = (ii) - lane + (__ffsll(mm) - 1);           \
                if (inn) {                                                    \
                    const int pos = cnt + __popcll((mm) & below);             \
                    if (pos < K_NEIGH) lidx[wave][pos] = (ii);                \
                }                                                             \
                cnt += __popcll(mm);                                          \
            }
        SUBIT(m0, in0, i)
        SUBIT(m1, in1, i + 64)
        SUBIT(m2, in2, i + 128)
        SUBIT(m3, in3, i + 192)
        #undef SUBIT
    }

    // make this wave's LDS writes visible to its own lanes
    asm volatile("s_waitcnt lgkmcnt(0)" ::: "memory");

    if (lane < K_NEIGH) {
        const int j = (lane < cnt) ? lidx[wave][lane] : ff;
        idxb[(size_t)q * K_NEIGH + lane] = j;
        const float gx = x0[j] - qx;
        const float gy = x1[j] - qy;
        const float gz = x2[j] - qz;
        const size_t MK = (size_t)M * K_NEIGH;
        const size_t o1 = (size_t)b * 3 * MK + (size_t)m * K_NEIGH + lane;
        out1[o1]          = gx;
        out1[o1 + MK]     = gy;
        out1[o1 + 2 * MK] = gz;
        if (use_xyz) {
            const size_t o0 = (size_t)b * (C + 3) * MK + (size_t)m * K_NEIGH + lane;
            out0[o0]          = gx;
            out0[o0 + MK]     = gy;
            out0[o0 + 2 * MK] = gz;
        }
    }
}

// Fixed geometry: B=4, N=8192, M=2048, C=128. Grid = 256 blocks x 1024 thr.
// bid -> b = (bid&7)>>1, cg = ((bid>>3)<<1)|(bid&1). Stage 64KB feat slab once,
// prefetch all idx (16x int4), then one store pass:
// per iter: int4 idx -> 8x ds_read_b32 -> 2x nontemporal float4 stores.
__global__ __launch_bounds__(1024, 4) void gather_onepass_kernel(
    const float* __restrict__ feat,  // (B,C,N)
    const int* __restrict__ idxb,    // (B*M,K)
    float* __restrict__ out0,        // (B,CO,M,K)
    int use_xyz)
{
    __shared__ float sf[2 * NPTS];   // 64 KB: [0,N) = ch c0, [N,2N) = ch c0+1

    const int t   = threadIdx.x;
    const int bid = blockIdx.x;
    const int b   = (bid & 7) >> 1;                 // 0..3
    const int cg  = ((bid >> 3) << 1) | (bid & 1);  // 0..63
    const int c0  = cg * 2;

    // ---- Phase A: idx prefetch (regs) + feat stage (LDS) ----
    const int4* ip4 = (const int4*)(idxb + (size_t)b * MQ * K_NEIGH);
    int4 jj[16];
    #pragma unroll
    for (int i = 0; i < 16; ++i) jj[i] = ip4[i * 1024 + t];

    const float4* fv = (const float4*)(feat + ((size_t)b * CCH + c0) * NPTS);
    #pragma unroll
    for (int r = 0; r < 4; ++r)
        ((float4*)sf)[t + r * 1024] = fv[t + r * 1024];
    __syncthreads();

    // ---- Phase B: pure LDS-read + nontemporal 16B/lane stores ----
    const size_t MK = (size_t)MQ * K_NEIGH;
    const int CO   = use_xyz ? (CCH + 3) : CCH;
    const int coff = use_xyz ? 3 : 0;
    float* o0 = out0 + ((size_t)b * CO + coff + c0) * MK;
    float* o1 = o0 + MK;

    #pragma unroll
    for (int i = 0; i < 16; ++i) {
        const int p = i * 4096 + 4 * t;      // flat (m,k) base, k-aligned x4
        const int4 j4 = jj[i];
        f32x4 s0, s1;
        s0.x = sf[j4.x]; s0.y = sf[j4.y]; s0.z = sf[j4.z]; s0.w = sf[j4.w];
        s1.x = sf[NPTS + j4.x]; s1.y = sf[NPTS + j4.y];
        s1.z = sf[NPTS + j4.z]; s1.w = sf[NPTS + j4.w];
        __builtin_nontemporal_store(s0, (f32x4*)(o0 + p));
        __builtin_nontemporal_store(s1, (f32x4*)(o1 + p));
    }
}

// Fallback gather (any shape): R1 structure.
__global__ __launch_bounds__(256) void gather_kernel(
    const float* __restrict__ xyz, const float* __restrict__ new_xyz,
    const float* __restrict__ feat, const int* __restrict__ idxb,
    float* __restrict__ out0, float* __restrict__ out1,
    int N, int M, int C, int use_xyz)
{
    const int tid = threadIdx.x;
    const int k = tid & 31;
    const int mloc = tid >> 5;
    const int mchunks = M >> 3;
    const int b = blockIdx.x / mchunks;
    const int m = (blockIdx.x - b * mchunks) * 8 + mloc;
    const int q = b * M + m;
    const int j = idxb[(size_t)q * K_NEIGH + k];
    const size_t xb = (size_t)b * 3 * N;
    const size_t nb = (size_t)b * 3 * M;
    const float gx = xyz[xb + j]         - new_xyz[nb + m];
    const float gy = xyz[xb + N + j]     - new_xyz[nb + M + m];
    const float gz = xyz[xb + 2 * N + j] - new_xyz[nb + 2 * M + m];
    const size_t MK = (size_t)M * K_NEIGH;
    const size_t o1 = (size_t)b * 3 * MK + (size_t)m * K_NEIGH + k;
    out1[o1] = gx; out1[o1 + MK] = gy; out1[o1 + 2 * MK] = gz;
    const int CO = use_xyz ? (C + 3) : C;
    size_t o0 = (size_t)b * CO * MK + (size_t)m * K_NEIGH + k;
    if (use_xyz) {
        out0[o0] = gx; out0[o0 + MK] = gy; out0[o0 + 2 * MK] = gz;
        o0 += 3 * MK;
    }
    const float* fb = feat + (size_t)b * C * N;
    #pragma unroll 4
    for (int c = 0; c < C; c += 4) {
        const float v0 = fb[(size_t)c * N + j];
        const float v1 = fb[(size_t)(c + 1) * N + j];
        const float v2 = fb[(size_t)(c + 2) * N + j];
        const float v3 = fb[(size_t)(c + 3) * N + j];
        out0[o0 + (size_t)c * MK]       = v0;
        out0[o0 + (size_t)(c + 1) * MK] = v1;
        out0[o0 + (size_t)(c + 2) * MK] = v2;
        out0[o0 + (size_t)(c + 3) * MK] = v3;
    }
}

extern "C" void kernel_launch(void* const* d_in, const int* in_sizes, int n_in,
                              void* d_out, int out_size, void* d_ws, size_t ws_size,
                              hipStream_t stream) {
    const float* new_xyz = (const float*)d_in[0];   // (B,3,M)
    const float* xyz     = (const float*)d_in[1];   // (B,3,N)
    const float* feat    = (const float*)d_in[2];   // (B,C,N)

    const int B = 4;                       // fixed by harness setup
    const int M = in_sizes[0] / (3 * B);   // 2048
    const int N = in_sizes[1] / (3 * B);   // 8192
    const int C = in_sizes[2] / (B * N);   // 128

    const long long sz_with = (long long)B * (C + 6) * M * K_NEIGH;
    const int use_xyz = (out_size == sz_with) ? 1 : 0;

    float* out0 = (float*)d_out;
    float* out1 = out0 + (size_t)B * (use_xyz ? (C + 3) : C) * M * K_NEIGH;

    int* idxb = (int*)d_ws;  // B*M*K ints = 1 MB
    const size_t idx_bytes = (size_t)B * M * K_NEIGH * sizeof(int);

    const bool fast = (B == 4) && (N == NPTS) && (M == MQ) && (C == CCH)
                      && (ws_size >= idx_bytes) && (N % 256 == 0);

    ball_query_xyz_kernel<<<(B * M) / 4, 256, 0, stream>>>(
        xyz, new_xyz, idxb, out0, out1, N, M, C, use_xyz);

    if (fast) {
        gather_onepass_kernel<<<256, 1024, 0, stream>>>(feat, idxb, out0, use_xyz);
    } else {
        gather_kernel<<<B * (M / 8), 256, 0, stream>>>(xyz, new_xyz, feat, idxb,
                                                       out0, out1, N, M, C, use_xyz);
    }
}